// Round 13
// baseline (107.939 us; speedup 1.0000x reference)
//
#include <hip/hip_runtime.h>
#include <hip/hip_bf16.h>

// GRU cell: B=16384, IN=256, UNITS=256, K = IN+UNITS = 512.
//   z = sigmoid([h,x]@Wz + bz); r = sigmoid([h,x]@Wr + br)
//   h~ = tanh([r*h, x]@Ws + bs);  h' = (1-z)*h + z*h~
// Round 10 (resubmit #3 after infra failures): NO A-staging. A-frags loaded
// straight from global fp32 with in-reg bf16 cvt (k-elems are contiguous per
// row). Only rh goes through LDS (16 KB). ONE barrier. 512-thr blocks,
// 32 rows, grid 512 -> 2 blocks/CU.

#define ROWS 32

typedef float f32x4 __attribute__((ext_vector_type(4)));
typedef __bf16 bf16x8 __attribute__((ext_vector_type(8)));
typedef unsigned short us8 __attribute__((ext_vector_type(8)));

static __device__ __forceinline__ unsigned short f2bf(float f) {
    __bf16 h = (__bf16)f;                              // RNE, enables v_cvt_pk
    return __builtin_bit_cast(unsigned short, h);
}

// A-frag: lane covers row (l&15), k = (l>>4)*8 + j. 8 consecutive fp32 of one
// row -> two float4 loads + packed cvt. Lines fully consumed across the wave.
static __device__ __forceinline__ bf16x8 ldA(const float* __restrict__ base,
                                             int row, int kk) {
    const float* p = base + (size_t)row * 256 + kk;
    float4 a = *(const float4*)p;
    float4 b = *(const float4*)(p + 4);
    us8 o;
    o[0] = f2bf(a.x); o[1] = f2bf(a.y); o[2] = f2bf(a.z); o[3] = f2bf(a.w);
    o[4] = f2bf(b.x); o[5] = f2bf(b.y); o[6] = f2bf(b.z); o[7] = f2bf(b.w);
    return __builtin_bit_cast(bf16x8, o);
}

// Pack W[512][256] (fp32 row-major) -> [kt][nt][lane][8] bf16 frags.
// Thread = one fragment row: reads 8 fp32 (stride 256), writes 16B coalesced.
__global__ void pack_weights(const float* __restrict__ Wz,
                             const float* __restrict__ Wr,
                             const float* __restrict__ Ws,
                             unsigned short* __restrict__ out) {
    int gid = blockIdx.x * blockDim.x + threadIdx.x;   // 0 .. 49152
    int w    = gid >> 14;
    int rem  = gid & 16383;
    int kt   = rem >> 10;
    int rem2 = rem & 1023;
    int nt   = rem2 >> 6;
    int lane = rem2 & 63;
    int hi = lane >> 4, lo = lane & 15;
    const float* W = (w == 0) ? Wz : (w == 1) ? Wr : Ws;
    const float* src = W + (size_t)(kt * 32 + hi * 8) * 256 + nt * 16 + lo;
    us8 o;
#pragma unroll
    for (int j = 0; j < 8; ++j) o[j] = f2bf(src[(size_t)j * 256]);
    *(us8*)&out[(size_t)w * 131072 + (size_t)(((kt * 16 + nt) * 64 + lane) * 8)] = o;
}

__launch_bounds__(512, 4)
__global__ void gru_main(const float* __restrict__ x,
                         const float* __restrict__ ph,
                         const float* __restrict__ bz,
                         const float* __restrict__ br,
                         const float* __restrict__ bs,
                         const unsigned short* __restrict__ Wp,
                         float* __restrict__ out) {
    __shared__ unsigned short rhb[ROWS * 256];         // 16 KiB, XOR-swizzled

    const int tid  = threadIdx.x;
    const int lane = tid & 63;
    const int wid  = tid >> 6;                         // 0..7: cols [wid*32,+32)
    const int brow = blockIdx.x * ROWS;

    const int l15   = lane & 15;
    const int hi    = lane >> 4;
    const int kg    = hi << 3;                         // k sub-offset 0,8,16,24
    const int rrow0 = hi * 4;                          // C/D row base
    const int c0    = wid * 32 + l15;
    const int c1    = c0 + 16;

    // B-frag bases: frag(kt,nt) at ((kt*16+nt)*64+lane)*8; nt0=wid*2.
    const unsigned short* WzB = Wp          + (size_t)(wid * 128 + lane) * 8;
    const unsigned short* WrB = WzB + 131072;
    const unsigned short* WsB = WzB + 262144;

    // prefetch kt=0 B frags (fly under p-loads)
    us8 z0n = *(const us8*)WzB;        us8 z1n = *(const us8*)(WzB + 512);
    us8 r0n = *(const us8*)WrB;        us8 r1n = *(const us8*)(WrB + 512);

    const float bz0 = bz[c0], bz1 = bz[c1];
    const float br0 = br[c0], br1 = br[c1];
    const float bs0 = bs[c0], bs1 = bs[c1];

    // prev_h (fp32, exact) for sigmoid/epilogue — independent, loads early
    float pst[2][2][4];
#pragma unroll
    for (int m = 0; m < 2; ++m)
#pragma unroll
        for (int t = 0; t < 2; ++t)
#pragma unroll
            for (int i = 0; i < 4; ++i)
                pst[m][t][i] = ph[(size_t)(brow + m * 16 + rrow0 + i) * 256
                                  + (t ? c1 : c0)];

    // ---- GEMM1a: z,r over ph half (kt 0..7), B depth-1 prefetch ----
    f32x4 accz[2][2] = {};
    f32x4 accr[2][2] = {};
#pragma unroll
    for (int kt = 0; kt < 8; ++kt) {
        bf16x8 z0 = __builtin_bit_cast(bf16x8, z0n), z1 = __builtin_bit_cast(bf16x8, z1n);
        bf16x8 r0 = __builtin_bit_cast(bf16x8, r0n), r1 = __builtin_bit_cast(bf16x8, r1n);
        size_t no = (size_t)(kt + 1) * 8192;
        z0n = *(const us8*)(WzB + no); z1n = *(const us8*)(WzB + no + 512);
        r0n = *(const us8*)(WrB + no); r1n = *(const us8*)(WrB + no + 512);
        int kk = kt * 32 + kg;
#pragma unroll
        for (int m = 0; m < 2; ++m) {
            bf16x8 a = ldA(ph, brow + m * 16 + l15, kk);
            accz[m][0] = __builtin_amdgcn_mfma_f32_16x16x32_bf16(a, z0, accz[m][0], 0, 0, 0);
            accz[m][1] = __builtin_amdgcn_mfma_f32_16x16x32_bf16(a, z1, accz[m][1], 0, 0, 0);
            accr[m][0] = __builtin_amdgcn_mfma_f32_16x16x32_bf16(a, r0, accr[m][0], 0, 0, 0);
            accr[m][1] = __builtin_amdgcn_mfma_f32_16x16x32_bf16(a, r1, accr[m][1], 0, 0, 0);
        }
    }
    // ---- GEMM1b: z,r over x half (kt 8..15) ----
#pragma unroll
    for (int kt = 8; kt < 16; ++kt) {
        bf16x8 z0 = __builtin_bit_cast(bf16x8, z0n), z1 = __builtin_bit_cast(bf16x8, z1n);
        bf16x8 r0 = __builtin_bit_cast(bf16x8, r0n), r1 = __builtin_bit_cast(bf16x8, r1n);
        if (kt < 15) {
            size_t no = (size_t)(kt + 1) * 8192;
            z0n = *(const us8*)(WzB + no); z1n = *(const us8*)(WzB + no + 512);
            r0n = *(const us8*)(WrB + no); r1n = *(const us8*)(WrB + no + 512);
        }
        int kk = (kt - 8) * 32 + kg;
#pragma unroll
        for (int m = 0; m < 2; ++m) {
            bf16x8 a = ldA(x, brow + m * 16 + l15, kk);
            accz[m][0] = __builtin_amdgcn_mfma_f32_16x16x32_bf16(a, z0, accz[m][0], 0, 0, 0);
            accz[m][1] = __builtin_amdgcn_mfma_f32_16x16x32_bf16(a, z1, accz[m][1], 0, 0, 0);
            accr[m][0] = __builtin_amdgcn_mfma_f32_16x16x32_bf16(a, r0, accr[m][0], 0, 0, 0);
            accr[m][1] = __builtin_amdgcn_mfma_f32_16x16x32_bf16(a, r1, accr[m][1], 0, 0, 0);
        }
    }

    // prefetch Ws kt=8 frags (consumed by GEMM2-x); fly under sigmoid VALU
    us8 s0n = *(const us8*)(WsB + (size_t)8 * 8192);
    us8 s1n = *(const us8*)(WsB + (size_t)8 * 8192 + 512);

    // ---- sigmoid; rh -> LDS (swizzled); keep z in accz, p in pst ----
#pragma unroll
    for (int m = 0; m < 2; ++m)
#pragma unroll
        for (int t = 0; t < 2; ++t)
#pragma unroll
            for (int i = 0; i < 4; ++i) {
                int lrow = m * 16 + rrow0 + i;
                float z = 1.f / (1.f + __expf(-(accz[m][t][i] + (t ? bz1 : bz0))));
                float r = 1.f / (1.f + __expf(-(accr[m][t][i] + (t ? br1 : br0))));
                accz[m][t][i] = z;
                rhb[lrow * 256 + ((t ? c1 : c0) ^ ((lrow & 7) << 3))]
                    = f2bf(r * pst[m][t][i]);
            }

    // ---- GEMM2-x: kt 8..15, A from global x (L1/L2-hot), no barrier ----
    f32x4 accs[2][2] = {};
#pragma unroll
    for (int kt = 8; kt < 16; ++kt) {
        bf16x8 s0 = __builtin_bit_cast(bf16x8, s0n), s1 = __builtin_bit_cast(bf16x8, s1n);
        if (kt < 15) {
            size_t no = (size_t)(kt + 1) * 8192;
            s0n = *(const us8*)(WsB + no); s1n = *(const us8*)(WsB + no + 512);
        }
        int kk = (kt - 8) * 32 + kg;
#pragma unroll
        for (int m = 0; m < 2; ++m) {
            bf16x8 a = ldA(x, brow + m * 16 + l15, kk);
            accs[m][0] = __builtin_amdgcn_mfma_f32_16x16x32_bf16(a, s0, accs[m][0], 0, 0, 0);
            accs[m][1] = __builtin_amdgcn_mfma_f32_16x16x32_bf16(a, s1, accs[m][1], 0, 0, 0);
        }
    }

    // prefetch Ws kt=0 before the barrier (hides barrier drain)
    s0n = *(const us8*)WsB;
    s1n = *(const us8*)(WsB + 512);
    __syncthreads();                                   // the ONLY barrier

    // ---- GEMM2-rh: kt 0..7, A from rhb ----
#pragma unroll
    for (int kt = 0; kt < 8; ++kt) {
        bf16x8 s0 = __builtin_bit_cast(bf16x8, s0n), s1 = __builtin_bit_cast(bf16x8, s1n);
        if (kt < 7) {
            size_t no = (size_t)(kt + 1) * 8192;
            s0n = *(const us8*)(WsB + no); s1n = *(const us8*)(WsB + no + 512);
        }
        int ak = kt * 32 + kg;
#pragma unroll
        for (int m = 0; m < 2; ++m) {
            int arow = m * 16 + l15;
            bf16x8 a = __builtin_bit_cast(bf16x8,
                *(const us8*)&rhb[arow * 256 + (ak ^ ((arow & 7) << 3))]);
            accs[m][0] = __builtin_amdgcn_mfma_f32_16x16x32_bf16(a, s0, accs[m][0], 0, 0, 0);
            accs[m][1] = __builtin_amdgcn_mfma_f32_16x16x32_bf16(a, s1, accs[m][1], 0, 0, 0);
        }
    }

    // ---- epilogue: h' = (1-z)*p + z*tanh(s+bs) ----
#pragma unroll
    for (int m = 0; m < 2; ++m)
#pragma unroll
        for (int t = 0; t < 2; ++t)
#pragma unroll
            for (int i = 0; i < 4; ++i) {
                float s = accs[m][t][i] + (t ? bs1 : bs0);
                float e = __expf(-2.f * fabsf(s));
                float th = (1.f - e) / (1.f + e);
                th = (s < 0.f) ? -th : th;
                float z = accz[m][t][i];
                float p = pst[m][t][i];
                out[(size_t)(brow + m * 16 + rrow0 + i) * 256 + (t ? c1 : c0)]
                    = (1.f - z) * p + z * th;
            }
}

extern "C" void kernel_launch(void* const* d_in, const int* in_sizes, int n_in,
                              void* d_out, int out_size, void* d_ws, size_t ws_size,
                              hipStream_t stream) {
    const float* x  = (const float*)d_in[0];
    const float* ph = (const float*)d_in[1];
    const float* Wz = (const float*)d_in[2];
    const float* bz = (const float*)d_in[3];
    const float* Wr = (const float*)d_in[4];
    const float* br = (const float*)d_in[5];
    const float* Ws = (const float*)d_in[6];
    const float* bs = (const float*)d_in[7];
    unsigned short* Wp = (unsigned short*)d_ws;        // 786432 bytes used

    hipLaunchKernelGGL(pack_weights, dim3(192), dim3(256), 0, stream, Wz, Wr, Ws, Wp);
    hipLaunchKernelGGL(gru_main, dim3(512), dim3(512), 0, stream,
                       x, ph, bz, br, bs, Wp, (float*)d_out);
}

// Round 14
// 33.799 us; speedup vs baseline: 3.1935x; 3.1935x over previous
//
#include <hip/hip_runtime.h>
#include <hip/hip_bf16.h>

// GRU cell: B=16384, IN=256, UNITS=256, K = IN+UNITS = 512.
//   z = sigmoid([h,x]@Wz + bz); r = sigmoid([h,x]@Wr + br)
//   h~ = tanh([r*h, x]@Ws + bs);  h' = (1-z)*h + z*h~
// Round 14: revert to r9 (LDS A-staging, K-split pipeline) + FUSE the
// candidate GEMM's x-half into GEMM1b: one A-frag feeds z,r,s MFMAs.
// Removes the separate GEMM2-x phase and its 32 ds_reads/wave.

#define ROWS 64

typedef float f32x4 __attribute__((ext_vector_type(4)));
typedef __bf16 bf16x8 __attribute__((ext_vector_type(8)));
typedef unsigned short us8 __attribute__((ext_vector_type(8)));
typedef unsigned short us4v __attribute__((ext_vector_type(4)));

static __device__ __forceinline__ unsigned short f2bf(float f) {
    __bf16 h = (__bf16)f;                              // RNE, enables v_cvt_pk
    return __builtin_bit_cast(unsigned short, h);
}
static __device__ __forceinline__ float bf2f(unsigned short u) {
    union { unsigned u; float f; } v; v.u = ((unsigned)u) << 16;
    return v.f;
}

// Pack W[512][256] (fp32 row-major) -> [kt][nt][lane][8] bf16 frags.
// Thread = one fragment row: reads 8 fp32 (stride 256, lane-coalesced),
// writes 16B coalesced.
__global__ void pack_weights(const float* __restrict__ Wz,
                             const float* __restrict__ Wr,
                             const float* __restrict__ Ws,
                             unsigned short* __restrict__ out) {
    int gid = blockIdx.x * blockDim.x + threadIdx.x;   // 0 .. 49152
    int w    = gid >> 14;
    int rem  = gid & 16383;
    int kt   = rem >> 10;
    int rem2 = rem & 1023;
    int nt   = rem2 >> 6;
    int lane = rem2 & 63;
    int hi = lane >> 4, lo = lane & 15;
    const float* W = (w == 0) ? Wz : (w == 1) ? Wr : Ws;
    const float* src = W + (size_t)(kt * 32 + hi * 8) * 256 + nt * 16 + lo;
    us8 o;
#pragma unroll
    for (int j = 0; j < 8; ++j) o[j] = f2bf(src[(size_t)j * 256]);
    *(us8*)&out[(size_t)w * 131072 + (size_t)(((kt * 16 + nt) * 64 + lane) * 8)] = o;
}

__launch_bounds__(1024, 4)
__global__ void gru_main(const float* __restrict__ x,
                         const float* __restrict__ ph,
                         const float* __restrict__ bz,
                         const float* __restrict__ br,
                         const float* __restrict__ bs,
                         const unsigned short* __restrict__ Wp,
                         float* __restrict__ out) {
    __shared__ unsigned short sm[ROWS * 512];          // 64 KiB: [ph | x], swizzled
    __shared__ unsigned short rh[ROWS * 256];          // 32 KiB: r*ph, swizzled

    const int tid  = threadIdx.x;
    const int lane = tid & 63;
    const int wid  = tid >> 6;                         // 0..15 = N-slice (nt)
    const int brow = blockIdx.x * ROWS;

    const int l15 = lane & 15;
    const int kg  = (lane >> 4) << 3;                  // k sub-offset 0,8,16,24
    const int col = wid * 16 + l15;

    const unsigned short* pz = Wp          + (size_t)((wid * 64 + lane) * 8);
    const unsigned short* pr = Wp + 131072 + (size_t)((wid * 64 + lane) * 8);
    const unsigned short* ps = Wp + 262144 + (size_t)((wid * 64 + lane) * 8);
    us8 b0n = *(const us8*)pz;                         // kt=0, flies during staging
    us8 b1n = *(const us8*)pr;
    float bzc = bz[col], brc = br[col], bsc = bs[col];

    // ---- stage ph -> k[0,256) as bf16, swizzled ----
#pragma unroll
    for (int it = 0; it < 4; ++it) {
        int i   = tid + it * 1024;                     // 4096 float4 total
        int row = i >> 6;
        int c4  = (i & 63) << 2;
        int swr = (row & 7) << 3;
        float4 a = *(const float4*)&ph[(size_t)(brow + row) * 256 + c4];
        us4v u; u.x = f2bf(a.x); u.y = f2bf(a.y); u.z = f2bf(a.z); u.w = f2bf(a.w);
        *(us4v*)&sm[row * 512 + (c4 ^ swr)] = u;
    }
    __syncthreads();                                   // bar1: ph staged

    // ---- x loads to regs: fly under GEMM1a ----
    float4 xr[4];
#pragma unroll
    for (int it = 0; it < 4; ++it) {
        int i   = tid + it * 1024;
        int row = i >> 6;
        int c4  = (i & 63) << 2;
        xr[it] = *(const float4*)&x[(size_t)(brow + row) * 256 + c4];
    }

    // ---- GEMM1a: z,r over ph half (kt 0..7), depth-1 B prefetch ----
    f32x4 accz[4] = {};
    f32x4 accr[4] = {};
#pragma unroll 4
    for (int kt = 0; kt < 8; ++kt) {
        bf16x8 B0 = __builtin_bit_cast(bf16x8, b0n);
        bf16x8 B1 = __builtin_bit_cast(bf16x8, b1n);
        b0n = *(const us8*)(pz + (size_t)(kt + 1) * 8192);
        b1n = *(const us8*)(pr + (size_t)(kt + 1) * 8192);
        int ak = kt * 32 + kg;
#pragma unroll
        for (int m = 0; m < 4; ++m) {
            int arow = m * 16 + l15;
            bf16x8 a = __builtin_bit_cast(bf16x8,
                *(const us8*)&sm[arow * 512 + (ak ^ ((arow & 7) << 3))]);
            accz[m] = __builtin_amdgcn_mfma_f32_16x16x32_bf16(a, B0, accz[m], 0, 0, 0);
            accr[m] = __builtin_amdgcn_mfma_f32_16x16x32_bf16(a, B1, accr[m], 0, 0, 0);
        }
    }

    // ---- write x (bf16) into k[256,512) ----
#pragma unroll
    for (int it = 0; it < 4; ++it) {
        int i   = tid + it * 1024;
        int row = i >> 6;
        int c4  = (i & 63) << 2;
        int swr = (row & 7) << 3;
        us4v v; v.x = f2bf(xr[it].x); v.y = f2bf(xr[it].y);
        v.z = f2bf(xr[it].z); v.w = f2bf(xr[it].w);
        *(us4v*)&sm[row * 512 + ((256 + c4) ^ swr)] = v;
    }
    __syncthreads();                                   // bar2: x staged

    // prefetch Ws kt=8,9 (consumed inside fused GEMM1b)
    us8 s0n = *(const us8*)(ps + (size_t)8 * 8192);
    us8 s1n = *(const us8*)(ps + (size_t)9 * 8192);

    // ---- GEMM1b FUSED: z,r AND candidate-x over x half (kt 8..15) ----
    // One A-frag read feeds 3 MFMAs (z, r, s): accs is sigmoid-independent
    // for the x half, so it shares the A loads instead of a separate phase.
    f32x4 accs[4] = {};
#pragma unroll 4
    for (int kt = 8; kt < 16; ++kt) {
        bf16x8 B0 = __builtin_bit_cast(bf16x8, b0n);
        bf16x8 B1 = __builtin_bit_cast(bf16x8, b1n);
        bf16x8 S  = __builtin_bit_cast(bf16x8, s0n);
        s0n = s1n;
        if (kt < 15) {
            size_t no = (size_t)(kt + 1) * 8192;
            b0n = *(const us8*)(pz + no);
            b1n = *(const us8*)(pr + no);
        }
        if (kt < 14) s1n = *(const us8*)(ps + (size_t)(kt + 2) * 8192);
        int ak = kt * 32 + kg;
#pragma unroll
        for (int m = 0; m < 4; ++m) {
            int arow = m * 16 + l15;
            bf16x8 a = __builtin_bit_cast(bf16x8,
                *(const us8*)&sm[arow * 512 + (ak ^ ((arow & 7) << 3))]);
            accz[m] = __builtin_amdgcn_mfma_f32_16x16x32_bf16(a, B0, accz[m], 0, 0, 0);
            accr[m] = __builtin_amdgcn_mfma_f32_16x16x32_bf16(a, B1, accr[m], 0, 0, 0);
            accs[m] = __builtin_amdgcn_mfma_f32_16x16x32_bf16(a, S,  accs[m], 0, 0, 0);
        }
    }

    // prefetch Ws kt=0,1 now: latency hides under the sigmoid VALU phase
    s0n = *(const us8*)ps;
    s1n = *(const us8*)(ps + 8192);

    // ---- sigmoid; rh -> separate buffer; stash p,z ----
    float pst[4][4];
    const int rrow0 = (lane >> 4) * 4;
#pragma unroll
    for (int m = 0; m < 4; ++m) {
#pragma unroll
        for (int i = 0; i < 4; ++i) {
            int lrow = m * 16 + rrow0 + i;
            int cs = col ^ ((lrow & 7) << 3);
            float p = bf2f(sm[lrow * 512 + cs]);
            float z = 1.f / (1.f + __expf(-(accz[m][i] + bzc)));
            float r = 1.f / (1.f + __expf(-(accr[m][i] + brc)));
            accz[m][i] = z;
            pst[m][i]  = p;
            rh[lrow * 256 + cs] = f2bf(r * p);
        }
    }
    __syncthreads();                                   // bar3: rh ready

    // ---- GEMM2-rh: kt 0..7 from rh, depth-2 Ws chain ----
#pragma unroll 4
    for (int kt = 0; kt < 8; ++kt) {
        bf16x8 B = __builtin_bit_cast(bf16x8, s0n);
        s0n = s1n;
        if (kt < 6) s1n = *(const us8*)(ps + (size_t)(kt + 2) * 8192);
        int ak = kt * 32 + kg;
#pragma unroll
        for (int m = 0; m < 4; ++m) {
            int arow = m * 16 + l15;
            bf16x8 a = __builtin_bit_cast(bf16x8,
                *(const us8*)&rh[arow * 256 + (ak ^ ((arow & 7) << 3))]);
            accs[m] = __builtin_amdgcn_mfma_f32_16x16x32_bf16(a, B, accs[m], 0, 0, 0);
        }
    }

    // ---- epilogue: h' = (1-z)*p + z*tanh(s+bs) ----
#pragma unroll
    for (int m = 0; m < 4; ++m) {
#pragma unroll
        for (int i = 0; i < 4; ++i) {
            float s = accs[m][i] + bsc;
            float e = __expf(-2.f * fabsf(s));
            float th = (1.f - e) / (1.f + e);
            th = (s < 0.f) ? -th : th;
            float z = accz[m][i];
            float p = pst[m][i];
            int grow = brow + m * 16 + rrow0 + i;
            out[(size_t)grow * 256 + col] = (1.f - z) * p + z * th;
        }
    }
}

extern "C" void kernel_launch(void* const* d_in, const int* in_sizes, int n_in,
                              void* d_out, int out_size, void* d_ws, size_t ws_size,
                              hipStream_t stream) {
    const float* x  = (const float*)d_in[0];
    const float* ph = (const float*)d_in[1];
    const float* Wz = (const float*)d_in[2];
    const float* bz = (const float*)d_in[3];
    const float* Wr = (const float*)d_in[4];
    const float* br = (const float*)d_in[5];
    const float* Ws = (const float*)d_in[6];
    const float* bs = (const float*)d_in[7];
    unsigned short* Wp = (unsigned short*)d_ws;        // 786432 bytes used

    hipLaunchKernelGGL(pack_weights, dim3(192), dim3(256), 0, stream, Wz, Wr, Ws, Wp);
    hipLaunchKernelGGL(gru_main, dim3(256), dim3(1024), 0, stream,
                       x, ph, bz, br, bs, Wp, (float*)d_out);
}